// Round 1
// baseline (568.373 us; speedup 1.0000x reference)
//
#include <hip/hip_runtime.h>
#include <hip/hip_bf16.h>

// ---------- types ----------
typedef __attribute__((ext_vector_type(8))) short short8;
typedef __attribute__((ext_vector_type(4))) float f32x4;

__device__ __forceinline__ unsigned short f2bf(float x) {
  union { float f; unsigned int u; } v; v.f = x;
  unsigned int r = v.u + 0x7FFFu + ((v.u >> 16) & 1u);
  return (unsigned short)(r >> 16);
}

// ---------- K1: LayerNorm -> bf16 ----------
__global__ __launch_bounds__(256) void ln_kernel(
    const float* __restrict__ seq, const float* __restrict__ g,
    const float* __restrict__ b, unsigned short* __restrict__ xnb) {
  int row = blockIdx.x;
  int tid = threadIdx.x;
  const float* x = seq + (size_t)row * 1024;
  float4 v = *(const float4*)(x + tid * 4);
  float s = v.x + v.y + v.z + v.w;
  float s2 = v.x * v.x + v.y * v.y + v.z * v.z + v.w * v.w;
#pragma unroll
  for (int off = 32; off; off >>= 1) { s += __shfl_down(s, off); s2 += __shfl_down(s2, off); }
  __shared__ float rs_[4], rs2_[4];
  int lane = tid & 63, wave = tid >> 6;
  if (lane == 0) { rs_[wave] = s; rs2_[wave] = s2; }
  __syncthreads();
  float sum = rs_[0] + rs_[1] + rs_[2] + rs_[3];
  float sum2 = rs2_[0] + rs2_[1] + rs2_[2] + rs2_[3];
  float mu = sum * (1.f / 1024.f);
  float var = sum2 * (1.f / 1024.f) - mu * mu;
  float rstd = rsqrtf(var + 1e-5f);
  float4 gg = *(const float4*)(g + tid * 4);
  float4 bb = *(const float4*)(b + tid * 4);
  ushort4 o;
  o.x = f2bf((v.x - mu) * rstd * gg.x + bb.x);
  o.y = f2bf((v.y - mu) * rstd * gg.y + bb.y);
  o.z = f2bf((v.z - mu) * rstd * gg.z + bb.z);
  o.w = f2bf((v.w - mu) * rstd * gg.w + bb.w);
  *(ushort4*)(xnb + (size_t)row * 1024 + tid * 4) = o;
}

// ---------- multi-segment bf16 MFMA GEMM: C[m,n] = act(A[m,:]·W[n,:] + bias)*scale (+add) ----------
// A: bf16 [256,K] row-major. W: f32 [N,K] row-major (converted on load). BM=256,BN=64,BK=64.
struct GemmSegs {
  const unsigned short* A[8];
  const float* W[8];
  const float* bias[8];
  const float* add[8];
  float* out[8];
  int N[8];
  int tile0[8];
  int act[8];     // 0 none, 1 silu, 2 sigmoid, 3 add(seq)
  float scale[8];
  int nseg;
  int K;
};

#define SA 88  // LDS row stride in shorts: 176B = 16B-aligned, 2-way-max bank aliasing

__global__ __launch_bounds__(256, 2) void gemm_multi(GemmSegs g) {
  __shared__ __align__(16) unsigned short As[256 * SA];
  __shared__ __align__(16) unsigned short Wsm[64 * SA];
  int tile = blockIdx.x;
  int s = 0;
  while (s + 1 < g.nseg && tile >= g.tile0[s + 1]) s++;
  int n0 = (tile - g.tile0[s]) * 64;
  const unsigned short* A = g.A[s];
  const float* W = g.W[s];
  int N = g.N[s];
  int Kd = g.K;
  int tid = threadIdx.x;
  int lane = tid & 63, wave = tid >> 6, quad = lane >> 4, l16 = lane & 15;

  f32x4 acc[4][4] = {};

  int a_c = (tid & 7) * 8;   // col chunk (8 shorts)
  int a_r = tid >> 3;        // 0..31
  int w_c = (tid & 15) * 4;  // col chunk (4 floats)
  int w_r = tid >> 4;        // 0..15

  for (int k0 = 0; k0 < Kd; k0 += 64) {
#pragma unroll
    for (int it = 0; it < 8; it++) {
      int m = it * 32 + a_r;
      uint4 d = *(const uint4*)(A + (size_t)m * Kd + k0 + a_c);
      *(uint4*)&As[m * SA + a_c] = d;
    }
#pragma unroll
    for (int it = 0; it < 4; it++) {
      int n = it * 16 + w_r;
      float4 w = make_float4(0.f, 0.f, 0.f, 0.f);
      if (n0 + n < N) w = *(const float4*)(W + (size_t)(n0 + n) * Kd + k0 + w_c);
      unsigned int u0 = (unsigned int)f2bf(w.x) | ((unsigned int)f2bf(w.y) << 16);
      unsigned int u1 = (unsigned int)f2bf(w.z) | ((unsigned int)f2bf(w.w) << 16);
      *(uint2*)&Wsm[n * SA + w_c] = make_uint2(u0, u1);
    }
    __syncthreads();
#pragma unroll
    for (int kc = 0; kc < 2; kc++) {
      int kb = kc * 32 + quad * 8;
      short8 af[4], bfr[4];
#pragma unroll
      for (int r = 0; r < 4; r++)
        af[r] = *(const short8*)&As[(wave * 64 + r * 16 + l16) * SA + kb];
#pragma unroll
      for (int c = 0; c < 4; c++)
        bfr[c] = *(const short8*)&Wsm[(c * 16 + l16) * SA + kb];
#pragma unroll
      for (int r = 0; r < 4; r++)
#pragma unroll
        for (int c = 0; c < 4; c++)
          acc[r][c] = __builtin_amdgcn_mfma_f32_16x16x32_bf16(af[r], bfr[c], acc[r][c], 0, 0, 0);
    }
    __syncthreads();
  }

  const float* bias = g.bias[s];
  const float* add = g.add[s];
  float* out = g.out[s];
  int act = g.act[s];
  float scale = g.scale[s];
#pragma unroll
  for (int c = 0; c < 4; c++) {
    int n = n0 + c * 16 + l16;
    if (n >= N) continue;
    float bv = bias ? bias[n] : 0.f;
#pragma unroll
    for (int r = 0; r < 4; r++) {
      int mb = wave * 64 + r * 16 + quad * 4;
#pragma unroll
      for (int j = 0; j < 4; j++) {
        float val = acc[r][c][j] + bv;
        if (act == 1) val = val / (1.f + __expf(-val));       // silu
        else if (act == 2) val = 1.f / (1.f + __expf(-val));  // sigmoid
        val *= scale;
        size_t idx = (size_t)(mb + j) * N + n;
        if (act == 3) val += add[idx];
        out[idx] = val;
      }
    }
  }
}

// ---------- K3: causal conv (K=4) along features + silu, emit bf16 x_c and bf16 x_t ----------
__global__ __launch_bounds__(256) void conv_kernel(
    const float* __restrict__ xt, const float* __restrict__ conv_w,
    const float* __restrict__ conv_b, unsigned short* __restrict__ xcb,
    unsigned short* __restrict__ xtb) {
  int b = blockIdx.x;
  int tid = threadIdx.x;
  const float* row = xt + (size_t)b * 2048;
  float w0 = conv_w[0], w1 = conv_w[1], w2 = conv_w[2], w3 = conv_w[3], cb = conv_b[0];
  for (int i = tid; i < 2048; i += 256) {
    float x3 = row[i];
    float x2 = (i >= 1) ? row[i - 1] : 0.f;
    float x1 = (i >= 2) ? row[i - 2] : 0.f;
    float x0 = (i >= 3) ? row[i - 3] : 0.f;
    float c = w0 * x0 + w1 * x1 + w2 * x2 + w3 * x3 + cb;
    c = c / (1.f + __expf(-c));  // silu
    xcb[(size_t)b * 2048 + i] = f2bf(c);
    xtb[(size_t)b * 2048 + i] = f2bf(x3);
  }
}

// ---------- K6: per-(b,h) cell: gating, c_t stream + num, n_t, GroupNorm, y ----------
__global__ __launch_bounds__(256) void cell_kernel(
    const float* __restrict__ c0, const float* __restrict__ n0,
    const float* __restrict__ m0, const float* __restrict__ qb,
    const float* __restrict__ kb, const float* __restrict__ vb,
    const float* __restrict__ ob, const float* __restrict__ skipb,
    const float* __restrict__ srb, const float* __restrict__ itb,
    const float* __restrict__ ftb, const float* __restrict__ gn_g,
    const float* __restrict__ gn_b, float* __restrict__ ct_out,
    float* __restrict__ nt_out, float* __restrict__ mt_out,
    unsigned short* __restrict__ yb) {
  int bh = blockIdx.x;
  int h = bh & 7;
  int tid = threadIdx.x;
  int lane = tid & 63, wave = tid >> 6;
  __shared__ float qs[128], ks[128], vs[128], num[128];
  __shared__ float r0[4], r1[4];

  float i_t = itb[bh], f_t = ftb[bh], m0v = m0[bh];
  float m_t = fmaxf(f_t + m0v, i_t);
  float i_e = __expf(i_t - m_t);
  float f_e = __expf(f_t - m_t + m0v);
  if (tid == 0) mt_out[bh] = m_t;

  size_t vbase = (size_t)bh * 128;
  float kq_p = 0.f, nq_p = 0.f, n0d = 0.f, kd = 0.f;
  if (tid < 128) {
    float qd = qb[vbase + tid];
    kd = kb[vbase + tid];
    n0d = n0[vbase + tid];
    qs[tid] = qd; ks[tid] = kd; vs[tid] = vb[vbase + tid];
    kq_p = kd * qd;
    nq_p = n0d * qd;
  }
#pragma unroll
  for (int off = 32; off; off >>= 1) { kq_p += __shfl_down(kq_p, off); nq_p += __shfl_down(nq_p, off); }
  if (lane == 0) { r0[wave] = kq_p; r1[wave] = nq_p; }
  __syncthreads();
  float kq = r0[0] + r0[1] + r0[2] + r0[3];
  float nq = r1[0] + r1[1] + r1[2] + r1[3];
  float den = fmaxf(f_e * nq + i_e * kq, 1.f);

  if (tid < 128) nt_out[vbase + tid] = f_e * n0d + i_e * kd;

  const float* c0p = c0 + (size_t)bh * 16384;
  float* ctp = ct_out + (size_t)bh * 16384;
  float k0v = ks[lane * 2], k1v = ks[lane * 2 + 1];
  float q0v = qs[lane * 2], q1v = qs[lane * 2 + 1];
#pragma unroll 4
  for (int i = 0; i < 32; i++) {
    int d = wave * 32 + i;
    float vd = vs[d];
    float2 cv = *(const float2*)(c0p + d * 128 + lane * 2);
    float cx = f_e * cv.x + i_e * vd * k0v;
    float cy = f_e * cv.y + i_e * vd * k1v;
    *(float2*)(ctp + d * 128 + lane * 2) = make_float2(cx, cy);
    float p = cx * q0v + cy * q1v;
#pragma unroll
    for (int off = 32; off; off >>= 1) p += __shfl_down(p, off);
    if (lane == 0) num[d] = p;
  }
  __syncthreads();

  float hval = 0.f;
  if (tid < 128) hval = ob[vbase + tid] * num[tid] / den;
  float s = hval, s2 = hval * hval;
#pragma unroll
  for (int off = 32; off; off >>= 1) { s += __shfl_down(s, off); s2 += __shfl_down(s2, off); }
  if (lane == 0) { r0[wave] = s; r1[wave] = s2; }
  __syncthreads();
  float mean = (r0[0] + r0[1] + r0[2] + r0[3]) * (1.f / 128.f);
  float var = (r1[0] + r1[1] + r1[2] + r1[3]) * (1.f / 128.f) - mean * mean;
  float rstd = rsqrtf(var + 1e-5f);
  if (tid < 128) {
    int ch = h * 128 + tid;
    float hn = (hval - mean) * rstd * gn_g[ch] + gn_b[ch];
    float y = (hn + skipb[vbase + tid]) * srb[vbase + tid];
    yb[vbase + tid] = f2bf(y);
  }
}

// ---------- launch ----------
extern "C" void kernel_launch(void* const* d_in, const int* in_sizes, int n_in,
                              void* d_out, int out_size, void* d_ws, size_t ws_size,
                              hipStream_t stream) {
  const float* seq   = (const float*)d_in[0];
  const float* c0    = (const float*)d_in[1];
  const float* n0    = (const float*)d_in[2];
  const float* m0    = (const float*)d_in[3];
  const float* ln_g  = (const float*)d_in[4];
  const float* ln_b  = (const float*)d_in[5];
  const float* gn_g  = (const float*)d_in[6];
  const float* gn_b  = (const float*)d_in[7];
  const float* W_upl = (const float*)d_in[8];
  const float* b_upl = (const float*)d_in[9];
  const float* W_upr = (const float*)d_in[10];
  const float* b_upr = (const float*)d_in[11];
  const float* W_down= (const float*)d_in[12];
  const float* b_down= (const float*)d_in[13];
  const float* conv_w= (const float*)d_in[14];
  const float* conv_b= (const float*)d_in[15];
  const float* W_skip= (const float*)d_in[16];
  const float* W_i   = (const float*)d_in[17];
  const float* b_i   = (const float*)d_in[18];
  const float* W_f   = (const float*)d_in[19];
  const float* b_f   = (const float*)d_in[20];
  const float* W_o   = (const float*)d_in[21];
  const float* b_o   = (const float*)d_in[22];
  const float* W_q   = (const float*)d_in[23];
  const float* b_q   = (const float*)d_in[24];
  const float* W_k   = (const float*)d_in[25];
  const float* b_k   = (const float*)d_in[26];
  const float* W_v   = (const float*)d_in[27];
  const float* b_v   = (const float*)d_in[28];

  float* out = (float*)d_out;          // [256,1024]
  float* ct  = out + 262144;           // [256,8,128,128]
  float* nt  = ct + 33554432;          // [256,8,128]
  float* mt  = nt + 262144;            // [256,8]

  char* ws = (char*)d_ws;
  unsigned short* xnb = (unsigned short*)(ws);             // 512KB bf16 [256,1024]
  unsigned short* xtb = (unsigned short*)(ws + 524288);    // 1MB bf16 [256,2048]
  unsigned short* xcb = (unsigned short*)(ws + 1572864);   // 1MB bf16 [256,2048]
  unsigned short* yb  = (unsigned short*)(ws + 2621440);   // 512KB bf16 [256,1024]
  float* xt  = (float*)(ws + 3145728);                     // 2MB [256,2048]
  float* sr  = (float*)(ws + 5242880);                     // 1MB silu(r_t)
  float* qb  = (float*)(ws + 6291456);                     // 1MB
  float* kb  = (float*)(ws + 7340032);                     // 1MB (pre-scaled)
  float* vb  = (float*)(ws + 8388608);                     // 1MB
  float* ob  = (float*)(ws + 9437184);                     // 1MB sigmoid(o)
  float* skb = (float*)(ws + 10485760);                    // 1MB
  float* itb = (float*)(ws + 11534336);                    // 8KB [256,8]
  float* ftb = (float*)(ws + 11542528);                    // 8KB [256,8]

  ln_kernel<<<256, 256, 0, stream>>>(seq, ln_g, ln_b, xnb);

  GemmSegs g1 = {};
  g1.nseg = 2; g1.K = 1024;
  g1.A[0] = xnb; g1.W[0] = W_upl; g1.bias[0] = b_upl; g1.out[0] = xt;
  g1.N[0] = 2048; g1.tile0[0] = 0;  g1.act[0] = 0; g1.scale[0] = 1.f;
  g1.A[1] = xnb; g1.W[1] = W_upr; g1.bias[1] = b_upr; g1.out[1] = sr;
  g1.N[1] = 1024; g1.tile0[1] = 32; g1.act[1] = 1; g1.scale[1] = 1.f;  // silu(r_t)
  gemm_multi<<<48, 256, 0, stream>>>(g1);

  conv_kernel<<<256, 256, 0, stream>>>(xt, conv_w, conv_b, xcb, xtb);

  GemmSegs g2 = {};
  g2.nseg = 7; g2.K = 2048;
  g2.A[0] = xcb; g2.W[0] = W_q;    g2.bias[0] = b_q;    g2.out[0] = qb;
  g2.N[0] = 1024; g2.tile0[0] = 0;  g2.act[0] = 0; g2.scale[0] = 1.f;
  g2.A[1] = xcb; g2.W[1] = W_k;    g2.bias[1] = b_k;    g2.out[1] = kb;
  g2.N[1] = 1024; g2.tile0[1] = 16; g2.act[1] = 0; g2.scale[1] = 0.088388347648318447f; // 1/sqrt(128)
  g2.A[2] = xtb; g2.W[2] = W_v;    g2.bias[2] = b_v;    g2.out[2] = vb;
  g2.N[2] = 1024; g2.tile0[2] = 32; g2.act[2] = 0; g2.scale[2] = 1.f;
  g2.A[3] = xtb; g2.W[3] = W_o;    g2.bias[3] = b_o;    g2.out[3] = ob;
  g2.N[3] = 1024; g2.tile0[3] = 48; g2.act[3] = 2; g2.scale[3] = 1.f;  // sigmoid
  g2.A[4] = xcb; g2.W[4] = W_skip; g2.bias[4] = nullptr; g2.out[4] = skb;
  g2.N[4] = 1024; g2.tile0[4] = 64; g2.act[4] = 0; g2.scale[4] = 1.f;
  g2.A[5] = xcb; g2.W[5] = W_i;    g2.bias[5] = b_i;    g2.out[5] = itb;
  g2.N[5] = 8;    g2.tile0[5] = 80; g2.act[5] = 0; g2.scale[5] = 1.f;
  g2.A[6] = xcb; g2.W[6] = W_f;    g2.bias[6] = b_f;    g2.out[6] = ftb;
  g2.N[6] = 8;    g2.tile0[6] = 81; g2.act[6] = 0; g2.scale[6] = 1.f;
  gemm_multi<<<82, 256, 0, stream>>>(g2);

  cell_kernel<<<2048, 256, 0, stream>>>(c0, n0, m0, qb, kb, vb, ob, skb, sr,
                                        itb, ftb, gn_g, gn_b, ct, nt, mt, yb);

  GemmSegs g3 = {};
  g3.nseg = 1; g3.K = 1024;
  g3.A[0] = yb; g3.W[0] = W_down; g3.bias[0] = b_down; g3.add[0] = seq; g3.out[0] = out;
  g3.N[0] = 1024; g3.tile0[0] = 0; g3.act[0] = 3; g3.scale[0] = 1.f;   // + b_down + seq
  gemm_multi<<<16, 256, 0, stream>>>(g3);
}

// Round 2
// 419.066 us; speedup vs baseline: 1.3563x; 1.3563x over previous
//
#include <hip/hip_runtime.h>
#include <hip/hip_bf16.h>

// ---------- types ----------
typedef __attribute__((ext_vector_type(8))) short short8;
typedef __attribute__((ext_vector_type(4))) float f32x4;

__device__ __forceinline__ unsigned short f2bf(float x) {
  union { float f; unsigned int u; } v; v.f = x;
  unsigned int r = v.u + 0x7FFFu + ((v.u >> 16) & 1u);
  return (unsigned short)(r >> 16);
}

// ---------- K1: LayerNorm -> bf16 ----------
__global__ __launch_bounds__(256) void ln_kernel(
    const float* __restrict__ seq, const float* __restrict__ g,
    const float* __restrict__ b, unsigned short* __restrict__ xnb) {
  int row = blockIdx.x;
  int tid = threadIdx.x;
  const float* x = seq + (size_t)row * 1024;
  float4 v = *(const float4*)(x + tid * 4);
  float s = v.x + v.y + v.z + v.w;
  float s2 = v.x * v.x + v.y * v.y + v.z * v.z + v.w * v.w;
#pragma unroll
  for (int off = 32; off; off >>= 1) { s += __shfl_down(s, off); s2 += __shfl_down(s2, off); }
  __shared__ float rs_[4], rs2_[4];
  int lane = tid & 63, wave = tid >> 6;
  if (lane == 0) { rs_[wave] = s; rs2_[wave] = s2; }
  __syncthreads();
  float sum = rs_[0] + rs_[1] + rs_[2] + rs_[3];
  float sum2 = rs2_[0] + rs2_[1] + rs2_[2] + rs2_[3];
  float mu = sum * (1.f / 1024.f);
  float var = sum2 * (1.f / 1024.f) - mu * mu;
  float rstd = rsqrtf(var + 1e-5f);
  float4 gg = *(const float4*)(g + tid * 4);
  float4 bb = *(const float4*)(b + tid * 4);
  ushort4 o;
  o.x = f2bf((v.x - mu) * rstd * gg.x + bb.x);
  o.y = f2bf((v.y - mu) * rstd * gg.y + bb.y);
  o.z = f2bf((v.z - mu) * rstd * gg.z + bb.z);
  o.w = f2bf((v.w - mu) * rstd * gg.w + bb.w);
  *(ushort4*)(xnb + (size_t)row * 1024 + tid * 4) = o;
}

// ---------- multi-segment bf16 MFMA GEMM ----------
// BM=64, BN=64, BK=64. grid.x = 4 * totalNtiles. bid&3 = M-tile, bid>>2 = N-tile idx.
// Register-prefetch double buffering: next K-slab's global loads issued between barriers.
struct GemmSegs {
  const unsigned short* A[8];
  const float* W[8];
  const float* bias[8];
  const float* add[8];
  float* out[8];
  int N[8];
  int tile0[8];   // in 64-wide N-tile units
  int act[8];     // 0 none, 1 silu, 2 sigmoid, 3 add(seq)
  float scale[8];
  int nseg;
  int K;
};

#define SB 72  // LDS row stride in shorts (144B): 16B-aligned, 2-way-max bank aliasing

__global__ __launch_bounds__(256, 4) void gemm_multi(GemmSegs g) {
  __shared__ __align__(16) unsigned short As[64 * SB];
  __shared__ __align__(16) unsigned short Ws[64 * SB];
  int bid = blockIdx.x;
  int m0 = (bid & 3) * 64;
  int tIdx = bid >> 2;
  int s = 0;
  while (s + 1 < g.nseg && tIdx >= g.tile0[s + 1]) s++;
  int n0 = (tIdx - g.tile0[s]) * 64;
  const unsigned short* A = g.A[s];
  const float* W = g.W[s];
  int N = g.N[s], Kd = g.K;
  int tid = threadIdx.x;
  int lane = tid & 63, wave = tid >> 6, quad = lane >> 4, l16 = lane & 15;

  f32x4 acc[4] = {};

  int r_ = tid >> 2;          // 0..63
  int c_ = (tid & 3) * 16;    // 0/16/32/48 (shorts for A, floats for W)

  const unsigned short* aRow = A + (size_t)(m0 + r_) * Kd + c_;
  const float* wRow = W + (size_t)(n0 + r_) * Kd + c_;
  bool wOk = (n0 + r_) < N;

  uint4 a0 = *(const uint4*)(aRow);
  uint4 a1 = *(const uint4*)(aRow + 8);
  float4 w0 = make_float4(0, 0, 0, 0), w1 = w0, w2 = w0, w3 = w0;
  if (wOk) {
    w0 = *(const float4*)(wRow);
    w1 = *(const float4*)(wRow + 4);
    w2 = *(const float4*)(wRow + 8);
    w3 = *(const float4*)(wRow + 12);
  }

  for (int k0 = 0; k0 < Kd; k0 += 64) {
    *(uint4*)&As[r_ * SB + c_] = a0;
    *(uint4*)&As[r_ * SB + c_ + 8] = a1;
    uint4 u0, u1;
    u0.x = (unsigned)f2bf(w0.x) | ((unsigned)f2bf(w0.y) << 16);
    u0.y = (unsigned)f2bf(w0.z) | ((unsigned)f2bf(w0.w) << 16);
    u0.z = (unsigned)f2bf(w1.x) | ((unsigned)f2bf(w1.y) << 16);
    u0.w = (unsigned)f2bf(w1.z) | ((unsigned)f2bf(w1.w) << 16);
    u1.x = (unsigned)f2bf(w2.x) | ((unsigned)f2bf(w2.y) << 16);
    u1.y = (unsigned)f2bf(w2.z) | ((unsigned)f2bf(w2.w) << 16);
    u1.z = (unsigned)f2bf(w3.x) | ((unsigned)f2bf(w3.y) << 16);
    u1.w = (unsigned)f2bf(w3.z) | ((unsigned)f2bf(w3.w) << 16);
    *(uint4*)&Ws[r_ * SB + c_] = u0;
    *(uint4*)&Ws[r_ * SB + c_ + 8] = u1;
    __syncthreads();
    if (k0 + 64 < Kd) {
      a0 = *(const uint4*)(aRow + k0 + 64);
      a1 = *(const uint4*)(aRow + k0 + 72);
      if (wOk) {
        w0 = *(const float4*)(wRow + k0 + 64);
        w1 = *(const float4*)(wRow + k0 + 68);
        w2 = *(const float4*)(wRow + k0 + 72);
        w3 = *(const float4*)(wRow + k0 + 76);
      }
    }
#pragma unroll
    for (int kc = 0; kc < 2; kc++) {
      int kb = kc * 32 + quad * 8;
      short8 af = *(const short8*)&As[(wave * 16 + l16) * SB + kb];
#pragma unroll
      for (int c = 0; c < 4; c++) {
        short8 bfr = *(const short8*)&Ws[(c * 16 + l16) * SB + kb];
        acc[c] = __builtin_amdgcn_mfma_f32_16x16x32_bf16(af, bfr, acc[c], 0, 0, 0);
      }
    }
    __syncthreads();
  }

  const float* bias = g.bias[s];
  const float* add = g.add[s];
  float* out = g.out[s];
  int act = g.act[s];
  float scale = g.scale[s];
#pragma unroll
  for (int c = 0; c < 4; c++) {
    int n = n0 + c * 16 + l16;
    if (n >= N) continue;
    float bv = bias ? bias[n] : 0.f;
#pragma unroll
    for (int j = 0; j < 4; j++) {
      int m = m0 + wave * 16 + quad * 4 + j;
      float val = acc[c][j] + bv;
      if (act == 1) val = val / (1.f + __expf(-val));       // silu
      else if (act == 2) val = 1.f / (1.f + __expf(-val));  // sigmoid
      val *= scale;
      size_t idx = (size_t)m * N + n;
      if (act == 3) val += add[idx];
      out[idx] = val;
    }
  }
}

// ---------- K3: causal conv (K=4) + silu via LDS row staging ----------
__global__ __launch_bounds__(256) void conv_kernel(
    const float* __restrict__ xt, const float* __restrict__ conv_w,
    const float* __restrict__ conv_b, unsigned short* __restrict__ xcb,
    unsigned short* __restrict__ xtb) {
  int b = blockIdx.x;
  int tid = threadIdx.x;
  __shared__ float xr[2048];
  const float* row = xt + (size_t)b * 2048;
#pragma unroll
  for (int it = 0; it < 2; it++) {
    int i = (it * 256 + tid) * 4;
    *(float4*)&xr[i] = *(const float4*)(row + i);
  }
  __syncthreads();
  float w0 = conv_w[0], w1 = conv_w[1], w2 = conv_w[2], w3 = conv_w[3], cb = conv_b[0];
#pragma unroll
  for (int it = 0; it < 2; it++) {
    int i0 = (it * 256 + tid) * 4;
    ushort4 oc, ot;
    unsigned short* pc = &oc.x;
    unsigned short* pt = &ot.x;
#pragma unroll
    for (int j = 0; j < 4; j++) {
      int i = i0 + j;
      float x3 = xr[i];
      float x2 = (i >= 1) ? xr[i - 1] : 0.f;
      float x1 = (i >= 2) ? xr[i - 2] : 0.f;
      float x0 = (i >= 3) ? xr[i - 3] : 0.f;
      float c = w0 * x0 + w1 * x1 + w2 * x2 + w3 * x3 + cb;
      c = c / (1.f + __expf(-c));
      pc[j] = f2bf(c);
      pt[j] = f2bf(x3);
    }
    *(ushort4*)(xcb + (size_t)b * 2048 + i0) = oc;
    *(ushort4*)(xtb + (size_t)b * 2048 + i0) = ot;
  }
}

// ---------- K6: per-(b,h) cell ----------
// wave handles 32 d-rows as 4 groups of 8; lane = (row-in-group)*8 + colblock;
// each lane owns 16 contiguous cols (k,q fragments in registers); 3 shfl_xor per group.
__global__ __launch_bounds__(256) void cell_kernel(
    const float* __restrict__ c0, const float* __restrict__ n0,
    const float* __restrict__ m0, const float* __restrict__ qb,
    const float* __restrict__ kb, const float* __restrict__ vb,
    const float* __restrict__ ob, const float* __restrict__ skipb,
    const float* __restrict__ srb, const float* __restrict__ itb,
    const float* __restrict__ ftb, const float* __restrict__ gn_g,
    const float* __restrict__ gn_b, float* __restrict__ ct_out,
    float* __restrict__ nt_out, float* __restrict__ mt_out,
    unsigned short* __restrict__ yb) {
  int bh = blockIdx.x;
  int h = bh & 7;
  int tid = threadIdx.x;
  int lane = tid & 63, wave = tid >> 6;
  __shared__ float qs[128], ks[128], vs[128], num[128];
  __shared__ float r0[4], r1[4];

  float i_t = itb[bh], f_t = ftb[bh], m0v = m0[bh];
  float m_t = fmaxf(f_t + m0v, i_t);
  float i_e = __expf(i_t - m_t);
  float f_e = __expf(f_t - m_t + m0v);
  if (tid == 0) mt_out[bh] = m_t;

  size_t vbase = (size_t)bh * 128;
  float kq_p = 0.f, nq_p = 0.f, n0d = 0.f, kd = 0.f;
  if (tid < 128) {
    float qd = qb[vbase + tid];
    kd = kb[vbase + tid];
    n0d = n0[vbase + tid];
    qs[tid] = qd; ks[tid] = kd; vs[tid] = vb[vbase + tid];
    kq_p = kd * qd;
    nq_p = n0d * qd;
  }
#pragma unroll
  for (int off = 32; off; off >>= 1) { kq_p += __shfl_down(kq_p, off); nq_p += __shfl_down(nq_p, off); }
  if (lane == 0) { r0[wave] = kq_p; r1[wave] = nq_p; }
  __syncthreads();
  float kq = r0[0] + r0[1] + r0[2] + r0[3];
  float nq = r1[0] + r1[1] + r1[2] + r1[3];
  float den = fmaxf(f_e * nq + i_e * kq, 1.f);

  if (tid < 128) nt_out[vbase + tid] = f_e * n0d + i_e * kd;

  int rsub = lane >> 3;     // 0..7
  int cblk = lane & 7;      // 0..7
  int ccol = cblk * 16;
  float kr[16], qr[16];
#pragma unroll
  for (int j = 0; j < 16; j += 4) {
    *(float4*)&kr[j] = *(const float4*)&ks[ccol + j];
    *(float4*)&qr[j] = *(const float4*)&qs[ccol + j];
  }
  const float* c0p = c0 + (size_t)bh * 16384;
  float* ctp = ct_out + (size_t)bh * 16384;
#pragma unroll
  for (int gI = 0; gI < 4; gI++) {
    int d = wave * 32 + gI * 8 + rsub;
    float iv = i_e * vs[d];
    const float* src = c0p + d * 128 + ccol;
    float* dst = ctp + d * 128 + ccol;
    float p = 0.f;
#pragma unroll
    for (int j = 0; j < 4; j++) {
      float4 cv = *(const float4*)(src + j * 4);
      float4 cn;
      cn.x = f_e * cv.x + iv * kr[j * 4 + 0];
      cn.y = f_e * cv.y + iv * kr[j * 4 + 1];
      cn.z = f_e * cv.z + iv * kr[j * 4 + 2];
      cn.w = f_e * cv.w + iv * kr[j * 4 + 3];
      *(float4*)(dst + j * 4) = cn;
      p += cn.x * qr[j * 4 + 0] + cn.y * qr[j * 4 + 1] +
           cn.z * qr[j * 4 + 2] + cn.w * qr[j * 4 + 3];
    }
    p += __shfl_xor(p, 1);
    p += __shfl_xor(p, 2);
    p += __shfl_xor(p, 4);
    if (cblk == 0) num[d] = p;
  }
  __syncthreads();

  float hval = 0.f;
  if (tid < 128) hval = ob[vbase + tid] * num[tid] / den;
  float s = hval, s2 = hval * hval;
#pragma unroll
  for (int off = 32; off; off >>= 1) { s += __shfl_down(s, off); s2 += __shfl_down(s2, off); }
  if (lane == 0) { r0[wave] = s; r1[wave] = s2; }
  __syncthreads();
  float mean = (r0[0] + r0[1] + r0[2] + r0[3]) * (1.f / 128.f);
  float var = (r1[0] + r1[1] + r1[2] + r1[3]) * (1.f / 128.f) - mean * mean;
  float rstd = rsqrtf(var + 1e-5f);
  if (tid < 128) {
    int ch = h * 128 + tid;
    float hn = (hval - mean) * rstd * gn_g[ch] + gn_b[ch];
    float y = (hn + skipb[vbase + tid]) * srb[vbase + tid];
    yb[vbase + tid] = f2bf(y);
  }
}

// ---------- launch ----------
extern "C" void kernel_launch(void* const* d_in, const int* in_sizes, int n_in,
                              void* d_out, int out_size, void* d_ws, size_t ws_size,
                              hipStream_t stream) {
  const float* seq   = (const float*)d_in[0];
  const float* c0    = (const float*)d_in[1];
  const float* n0    = (const float*)d_in[2];
  const float* m0    = (const float*)d_in[3];
  const float* ln_g  = (const float*)d_in[4];
  const float* ln_b  = (const float*)d_in[5];
  const float* gn_g  = (const float*)d_in[6];
  const float* gn_b  = (const float*)d_in[7];
  const float* W_upl = (const float*)d_in[8];
  const float* b_upl = (const float*)d_in[9];
  const float* W_upr = (const float*)d_in[10];
  const float* b_upr = (const float*)d_in[11];
  const float* W_down= (const float*)d_in[12];
  const float* b_down= (const float*)d_in[13];
  const float* conv_w= (const float*)d_in[14];
  const float* conv_b= (const float*)d_in[15];
  const float* W_skip= (const float*)d_in[16];
  const float* W_i   = (const float*)d_in[17];
  const float* b_i   = (const float*)d_in[18];
  const float* W_f   = (const float*)d_in[19];
  const float* b_f   = (const float*)d_in[20];
  const float* W_o   = (const float*)d_in[21];
  const float* b_o   = (const float*)d_in[22];
  const float* W_q   = (const float*)d_in[23];
  const float* b_q   = (const float*)d_in[24];
  const float* W_k   = (const float*)d_in[25];
  const float* b_k   = (const float*)d_in[26];
  const float* W_v   = (const float*)d_in[27];
  const float* b_v   = (const float*)d_in[28];

  float* out = (float*)d_out;          // [256,1024]
  float* ct  = out + 262144;           // [256,8,128,128]
  float* nt  = ct + 33554432;          // [256,8,128]
  float* mt  = nt + 262144;            // [256,8]

  char* ws = (char*)d_ws;
  unsigned short* xnb = (unsigned short*)(ws);             // 512KB bf16 [256,1024]
  unsigned short* xtb = (unsigned short*)(ws + 524288);    // 1MB bf16 [256,2048]
  unsigned short* xcb = (unsigned short*)(ws + 1572864);   // 1MB bf16 [256,2048]
  unsigned short* yb  = (unsigned short*)(ws + 2621440);   // 512KB bf16 [256,1024]
  float* xt  = (float*)(ws + 3145728);                     // 2MB [256,2048]
  float* sr  = (float*)(ws + 5242880);                     // 1MB silu(r_t)
  float* qb  = (float*)(ws + 6291456);                     // 1MB
  float* kb  = (float*)(ws + 7340032);                     // 1MB (pre-scaled)
  float* vb  = (float*)(ws + 8388608);                     // 1MB
  float* ob  = (float*)(ws + 9437184);                     // 1MB sigmoid(o)
  float* skb = (float*)(ws + 10485760);                    // 1MB
  float* itb = (float*)(ws + 11534336);                    // 8KB [256,8]
  float* ftb = (float*)(ws + 11542528);                    // 8KB [256,8]

  ln_kernel<<<256, 256, 0, stream>>>(seq, ln_g, ln_b, xnb);

  GemmSegs g1 = {};
  g1.nseg = 2; g1.K = 1024;
  g1.A[0] = xnb; g1.W[0] = W_upl; g1.bias[0] = b_upl; g1.out[0] = xt;
  g1.N[0] = 2048; g1.tile0[0] = 0;  g1.act[0] = 0; g1.scale[0] = 1.f;
  g1.A[1] = xnb; g1.W[1] = W_upr; g1.bias[1] = b_upr; g1.out[1] = sr;
  g1.N[1] = 1024; g1.tile0[1] = 32; g1.act[1] = 1; g1.scale[1] = 1.f;  // silu(r_t)
  gemm_multi<<<48 * 4, 256, 0, stream>>>(g1);

  conv_kernel<<<256, 256, 0, stream>>>(xt, conv_w, conv_b, xcb, xtb);

  GemmSegs g2 = {};
  g2.nseg = 7; g2.K = 2048;
  g2.A[0] = xcb; g2.W[0] = W_q;    g2.bias[0] = b_q;    g2.out[0] = qb;
  g2.N[0] = 1024; g2.tile0[0] = 0;  g2.act[0] = 0; g2.scale[0] = 1.f;
  g2.A[1] = xcb; g2.W[1] = W_k;    g2.bias[1] = b_k;    g2.out[1] = kb;
  g2.N[1] = 1024; g2.tile0[1] = 16; g2.act[1] = 0; g2.scale[1] = 0.088388347648318447f; // 1/sqrt(128)
  g2.A[2] = xtb; g2.W[2] = W_v;    g2.bias[2] = b_v;    g2.out[2] = vb;
  g2.N[2] = 1024; g2.tile0[2] = 32; g2.act[2] = 0; g2.scale[2] = 1.f;
  g2.A[3] = xtb; g2.W[3] = W_o;    g2.bias[3] = b_o;    g2.out[3] = ob;
  g2.N[3] = 1024; g2.tile0[3] = 48; g2.act[3] = 2; g2.scale[3] = 1.f;  // sigmoid
  g2.A[4] = xcb; g2.W[4] = W_skip; g2.bias[4] = nullptr; g2.out[4] = skb;
  g2.N[4] = 1024; g2.tile0[4] = 64; g2.act[4] = 0; g2.scale[4] = 1.f;
  g2.A[5] = xcb; g2.W[5] = W_i;    g2.bias[5] = b_i;    g2.out[5] = itb;
  g2.N[5] = 8;    g2.tile0[5] = 80; g2.act[5] = 0; g2.scale[5] = 1.f;
  g2.A[6] = xcb; g2.W[6] = W_f;    g2.bias[6] = b_f;    g2.out[6] = ftb;
  g2.N[6] = 8;    g2.tile0[6] = 81; g2.act[6] = 0; g2.scale[6] = 1.f;
  gemm_multi<<<82 * 4, 256, 0, stream>>>(g2);

  cell_kernel<<<2048, 256, 0, stream>>>(c0, n0, m0, qb, kb, vb, ob, skb, sr,
                                        itb, ftb, gn_g, gn_b, ct, nt, mt, yb);

  GemmSegs g3 = {};
  g3.nseg = 1; g3.K = 1024;
  g3.A[0] = yb; g3.W[0] = W_down; g3.bias[0] = b_down; g3.add[0] = seq; g3.out[0] = out;
  g3.N[0] = 1024; g3.tile0[0] = 0; g3.act[0] = 3; g3.scale[0] = 1.f;   // + b_down + seq
  gemm_multi<<<16 * 4, 256, 0, stream>>>(g3);
}

// Round 3
// 398.401 us; speedup vs baseline: 1.4266x; 1.0519x over previous
//
#include <hip/hip_runtime.h>
#include <hip/hip_bf16.h>

// ---------- types ----------
typedef __attribute__((ext_vector_type(8))) short short8;
typedef __attribute__((ext_vector_type(4))) float f32x4;

__device__ __forceinline__ unsigned short f2bf(float x) {
  union { float f; unsigned int u; } v; v.f = x;
  unsigned int r = v.u + 0x7FFFu + ((v.u >> 16) & 1u);
  return (unsigned short)(r >> 16);
}

// ---------- K0: convert f32 weights -> bf16 (once per launch) ----------
struct PrepSegs {
  const float* src[10];
  unsigned short* dst[10];
  int blk0[10];   // first block of each segment; each block converts 8192 elems
  int nseg;
};

__global__ __launch_bounds__(256) void prep_kernel(PrepSegs p) {
  int bid = blockIdx.x;
  int s = 0;
  while (s + 1 < p.nseg && bid >= p.blk0[s + 1]) s++;
  size_t off = (size_t)(bid - p.blk0[s]) * 8192;
  const float* src = p.src[s] + off;
  unsigned short* dst = p.dst[s] + off;
  int tid = threadIdx.x;
#pragma unroll
  for (int j = 0; j < 4; j++) {
    int i = (j * 256 + tid) * 8;
    float4 a = *(const float4*)(src + i);
    float4 b = *(const float4*)(src + i + 4);
    uint4 o;
    o.x = (unsigned)f2bf(a.x) | ((unsigned)f2bf(a.y) << 16);
    o.y = (unsigned)f2bf(a.z) | ((unsigned)f2bf(a.w) << 16);
    o.z = (unsigned)f2bf(b.x) | ((unsigned)f2bf(b.y) << 16);
    o.w = (unsigned)f2bf(b.z) | ((unsigned)f2bf(b.w) << 16);
    *(uint4*)(dst + i) = o;
  }
}

// ---------- K1: LayerNorm -> bf16 ----------
__global__ __launch_bounds__(256) void ln_kernel(
    const float* __restrict__ seq, const float* __restrict__ g,
    const float* __restrict__ b, unsigned short* __restrict__ xnb) {
  int row = blockIdx.x;
  int tid = threadIdx.x;
  const float* x = seq + (size_t)row * 1024;
  float4 v = *(const float4*)(x + tid * 4);
  float s = v.x + v.y + v.z + v.w;
  float s2 = v.x * v.x + v.y * v.y + v.z * v.z + v.w * v.w;
#pragma unroll
  for (int off = 32; off; off >>= 1) { s += __shfl_down(s, off); s2 += __shfl_down(s2, off); }
  __shared__ float rs_[4], rs2_[4];
  int lane = tid & 63, wave = tid >> 6;
  if (lane == 0) { rs_[wave] = s; rs2_[wave] = s2; }
  __syncthreads();
  float sum = rs_[0] + rs_[1] + rs_[2] + rs_[3];
  float sum2 = rs2_[0] + rs2_[1] + rs2_[2] + rs2_[3];
  float mu = sum * (1.f / 1024.f);
  float var = sum2 * (1.f / 1024.f) - mu * mu;
  float rstd = rsqrtf(var + 1e-5f);
  float4 gg = *(const float4*)(g + tid * 4);
  float4 bb = *(const float4*)(b + tid * 4);
  ushort4 o;
  o.x = f2bf((v.x - mu) * rstd * gg.x + bb.x);
  o.y = f2bf((v.y - mu) * rstd * gg.y + bb.y);
  o.z = f2bf((v.z - mu) * rstd * gg.z + bb.z);
  o.w = f2bf((v.w - mu) * rstd * gg.w + bb.w);
  *(ushort4*)(xnb + (size_t)row * 1024 + tid * 4) = o;
}

// ---------- multi-segment bf16 MFMA GEMM ----------
// BM=64, BN=64, BK=64. grid.x = 4 * totalNtiles. bid&3 = M-tile, bid>>2 = N-tile.
// A and W both bf16 row-major. Register-prefetch double buffering.
struct GemmSegs {
  const unsigned short* A[8];
  const unsigned short* W[8];
  const float* bias[8];
  const float* add[8];
  float* out[8];
  int N[8];
  int tile0[8];   // in 64-wide N-tile units
  int act[8];     // 0 none, 1 silu, 2 sigmoid, 3 add(seq)
  float scale[8];
  int nseg;
  int K;
};

#define SB 72  // LDS row stride in shorts (144B): 16B-aligned, 2-way-max bank aliasing

__global__ __launch_bounds__(256, 4) void gemm_multi(GemmSegs g) {
  __shared__ __align__(16) unsigned short As[64 * SB];
  __shared__ __align__(16) unsigned short Ws[64 * SB];
  int bid = blockIdx.x;
  int m0 = (bid & 3) * 64;
  int tIdx = bid >> 2;
  int s = 0;
  while (s + 1 < g.nseg && tIdx >= g.tile0[s + 1]) s++;
  int n0 = (tIdx - g.tile0[s]) * 64;
  const unsigned short* A = g.A[s];
  const unsigned short* W = g.W[s];
  int N = g.N[s], Kd = g.K;
  int tid = threadIdx.x;
  int lane = tid & 63, wave = tid >> 6, quad = lane >> 4, l16 = lane & 15;

  f32x4 acc[4] = {};

  int r_ = tid >> 2;          // 0..63
  int c_ = (tid & 3) * 16;    // 0/16/32/48 shorts

  const unsigned short* aRow = A + (size_t)(m0 + r_) * Kd + c_;
  const unsigned short* wRow = W + (size_t)(n0 + r_) * Kd + c_;
  bool wOk = (n0 + r_) < N;

  uint4 zz = make_uint4(0, 0, 0, 0);
  uint4 a0 = *(const uint4*)(aRow);
  uint4 a1 = *(const uint4*)(aRow + 8);
  uint4 w0 = zz, w1 = zz;
  if (wOk) {
    w0 = *(const uint4*)(wRow);
    w1 = *(const uint4*)(wRow + 8);
  }

  for (int k0 = 0; k0 < Kd; k0 += 64) {
    *(uint4*)&As[r_ * SB + c_] = a0;
    *(uint4*)&As[r_ * SB + c_ + 8] = a1;
    *(uint4*)&Ws[r_ * SB + c_] = w0;
    *(uint4*)&Ws[r_ * SB + c_ + 8] = w1;
    __syncthreads();
    if (k0 + 64 < Kd) {
      a0 = *(const uint4*)(aRow + k0 + 64);
      a1 = *(const uint4*)(aRow + k0 + 72);
      if (wOk) {
        w0 = *(const uint4*)(wRow + k0 + 64);
        w1 = *(const uint4*)(wRow + k0 + 72);
      }
    }
#pragma unroll
    for (int kc = 0; kc < 2; kc++) {
      int kb = kc * 32 + quad * 8;
      short8 af = *(const short8*)&As[(wave * 16 + l16) * SB + kb];
#pragma unroll
      for (int c = 0; c < 4; c++) {
        short8 bfr = *(const short8*)&Ws[(c * 16 + l16) * SB + kb];
        acc[c] = __builtin_amdgcn_mfma_f32_16x16x32_bf16(af, bfr, acc[c], 0, 0, 0);
      }
    }
    __syncthreads();
  }

  const float* bias = g.bias[s];
  const float* add = g.add[s];
  float* out = g.out[s];
  int act = g.act[s];
  float scale = g.scale[s];
#pragma unroll
  for (int c = 0; c < 4; c++) {
    int n = n0 + c * 16 + l16;
    if (n >= N) continue;
    float bv = bias ? bias[n] : 0.f;
#pragma unroll
    for (int j = 0; j < 4; j++) {
      int m = m0 + wave * 16 + quad * 4 + j;
      float val = acc[c][j] + bv;
      if (act == 1) val = val / (1.f + __expf(-val));       // silu
      else if (act == 2) val = 1.f / (1.f + __expf(-val));  // sigmoid
      val *= scale;
      size_t idx = (size_t)m * N + n;
      if (act == 3) val += add[idx];
      out[idx] = val;
    }
  }
}

// ---------- K3: causal conv (K=4) + silu via LDS row staging ----------
__global__ __launch_bounds__(256) void conv_kernel(
    const float* __restrict__ xt, const float* __restrict__ conv_w,
    const float* __restrict__ conv_b, unsigned short* __restrict__ xcb,
    unsigned short* __restrict__ xtb) {
  int b = blockIdx.x;
  int tid = threadIdx.x;
  __shared__ float xr[2048];
  const float* row = xt + (size_t)b * 2048;
#pragma unroll
  for (int it = 0; it < 2; it++) {
    int i = (it * 256 + tid) * 4;
    *(float4*)&xr[i] = *(const float4*)(row + i);
  }
  __syncthreads();
  float w0 = conv_w[0], w1 = conv_w[1], w2 = conv_w[2], w3 = conv_w[3], cb = conv_b[0];
#pragma unroll
  for (int it = 0; it < 2; it++) {
    int i0 = (it * 256 + tid) * 4;
    ushort4 oc, ot;
    unsigned short* pc = &oc.x;
    unsigned short* pt = &ot.x;
#pragma unroll
    for (int j = 0; j < 4; j++) {
      int i = i0 + j;
      float x3 = xr[i];
      float x2 = (i >= 1) ? xr[i - 1] : 0.f;
      float x1 = (i >= 2) ? xr[i - 2] : 0.f;
      float x0 = (i >= 3) ? xr[i - 3] : 0.f;
      float c = w0 * x0 + w1 * x1 + w2 * x2 + w3 * x3 + cb;
      c = c / (1.f + __expf(-c));
      pc[j] = f2bf(c);
      pt[j] = f2bf(x3);
    }
    *(ushort4*)(xcb + (size_t)b * 2048 + i0) = oc;
    *(ushort4*)(xtb + (size_t)b * 2048 + i0) = ot;
  }
}

// ---------- K6: per-(b,h) cell, fully-coalesced c0/c_t stream ----------
// Flat float4 layout: wave covers 2 full 128-col rows per load (1KB coalesced).
// Row dot: 5 shfl_xor within 32-lane halves. k/q fragments loop-invariant in regs.
__global__ __launch_bounds__(256) void cell_kernel(
    const float* __restrict__ c0, const float* __restrict__ n0,
    const float* __restrict__ m0, const float* __restrict__ qb,
    const float* __restrict__ kb, const float* __restrict__ vb,
    const float* __restrict__ ob, const float* __restrict__ skipb,
    const float* __restrict__ srb, const float* __restrict__ itb,
    const float* __restrict__ ftb, const float* __restrict__ gn_g,
    const float* __restrict__ gn_b, float* __restrict__ ct_out,
    float* __restrict__ nt_out, float* __restrict__ mt_out,
    unsigned short* __restrict__ yb) {
  int bh = blockIdx.x;
  int h = bh & 7;
  int tid = threadIdx.x;
  int lane = tid & 63, wave = tid >> 6;
  __shared__ float qs[128], ks[128], vs[128], num[128];
  __shared__ float r0[4], r1[4];

  float i_t = itb[bh], f_t = ftb[bh], m0v = m0[bh];
  float m_t = fmaxf(f_t + m0v, i_t);
  float i_e = __expf(i_t - m_t);
  float f_e = __expf(f_t - m_t + m0v);
  if (tid == 0) mt_out[bh] = m_t;

  size_t vbase = (size_t)bh * 128;
  float kq_p = 0.f, nq_p = 0.f, n0d = 0.f, kd = 0.f;
  if (tid < 128) {
    float qd = qb[vbase + tid];
    kd = kb[vbase + tid];
    n0d = n0[vbase + tid];
    qs[tid] = qd; ks[tid] = kd; vs[tid] = vb[vbase + tid];
    kq_p = kd * qd;
    nq_p = n0d * qd;
  }
#pragma unroll
  for (int off = 32; off; off >>= 1) { kq_p += __shfl_down(kq_p, off); nq_p += __shfl_down(nq_p, off); }
  if (lane == 0) { r0[wave] = kq_p; r1[wave] = nq_p; }
  __syncthreads();
  float kq = r0[0] + r0[1] + r0[2] + r0[3];
  float nq = r1[0] + r1[1] + r1[2] + r1[3];
  float den = fmaxf(f_e * nq + i_e * kq, 1.f);

  if (tid < 128) nt_out[vbase + tid] = f_e * n0d + i_e * kd;

  int col = (tid & 31) * 4;            // fixed 4-col fragment per lane
  int drow = tid >> 5;                 // 0..7, row-within-pass
  float4 kr = *(const float4*)&ks[col];
  float4 qr = *(const float4*)&qs[col];
  const float* c0p = c0 + (size_t)bh * 16384;
  float* ctp = ct_out + (size_t)bh * 16384;
#pragma unroll 4
  for (int pass = 0; pass < 16; pass++) {
    int d = pass * 8 + drow;
    float iv = i_e * vs[d];
    float4 cv = *(const float4*)(c0p + d * 128 + col);
    float4 cn;
    cn.x = f_e * cv.x + iv * kr.x;
    cn.y = f_e * cv.y + iv * kr.y;
    cn.z = f_e * cv.z + iv * kr.z;
    cn.w = f_e * cv.w + iv * kr.w;
    *(float4*)(ctp + d * 128 + col) = cn;
    float p = cn.x * qr.x + cn.y * qr.y + cn.z * qr.z + cn.w * qr.w;
    p += __shfl_xor(p, 1);
    p += __shfl_xor(p, 2);
    p += __shfl_xor(p, 4);
    p += __shfl_xor(p, 8);
    p += __shfl_xor(p, 16);
    if ((tid & 31) == 0) num[d] = p;
  }
  __syncthreads();

  float hval = 0.f;
  if (tid < 128) hval = ob[vbase + tid] * num[tid] / den;
  float s = hval, s2 = hval * hval;
#pragma unroll
  for (int off = 32; off; off >>= 1) { s += __shfl_down(s, off); s2 += __shfl_down(s2, off); }
  if (lane == 0) { r0[wave] = s; r1[wave] = s2; }
  __syncthreads();
  float mean = (r0[0] + r0[1] + r0[2] + r0[3]) * (1.f / 128.f);
  float var = (r1[0] + r1[1] + r1[2] + r1[3]) * (1.f / 128.f) - mean * mean;
  float rstd = rsqrtf(var + 1e-5f);
  if (tid < 128) {
    int ch = h * 128 + tid;
    float hn = (hval - mean) * rstd * gn_g[ch] + gn_b[ch];
    float y = (hn + skipb[vbase + tid]) * srb[vbase + tid];
    yb[vbase + tid] = f2bf(y);
  }
}

// ---------- launch ----------
extern "C" void kernel_launch(void* const* d_in, const int* in_sizes, int n_in,
                              void* d_out, int out_size, void* d_ws, size_t ws_size,
                              hipStream_t stream) {
  const float* seq   = (const float*)d_in[0];
  const float* c0    = (const float*)d_in[1];
  const float* n0    = (const float*)d_in[2];
  const float* m0    = (const float*)d_in[3];
  const float* ln_g  = (const float*)d_in[4];
  const float* ln_b  = (const float*)d_in[5];
  const float* gn_g  = (const float*)d_in[6];
  const float* gn_b  = (const float*)d_in[7];
  const float* W_upl = (const float*)d_in[8];
  const float* b_upl = (const float*)d_in[9];
  const float* W_upr = (const float*)d_in[10];
  const float* b_upr = (const float*)d_in[11];
  const float* W_down= (const float*)d_in[12];
  const float* b_down= (const float*)d_in[13];
  const float* conv_w= (const float*)d_in[14];
  const float* conv_b= (const float*)d_in[15];
  const float* W_skip= (const float*)d_in[16];
  const float* W_i   = (const float*)d_in[17];
  const float* b_i   = (const float*)d_in[18];
  const float* W_f   = (const float*)d_in[19];
  const float* b_f   = (const float*)d_in[20];
  const float* W_o   = (const float*)d_in[21];
  const float* b_o   = (const float*)d_in[22];
  const float* W_q   = (const float*)d_in[23];
  const float* b_q   = (const float*)d_in[24];
  const float* W_k   = (const float*)d_in[25];
  const float* b_k   = (const float*)d_in[26];
  const float* W_v   = (const float*)d_in[27];
  const float* b_v   = (const float*)d_in[28];

  float* out = (float*)d_out;          // [256,1024]
  float* ct  = out + 262144;           // [256,8,128,128]
  float* nt  = ct + 33554432;          // [256,8,128]
  float* mt  = nt + 262144;            // [256,8]

  char* ws = (char*)d_ws;
  unsigned short* xnb = (unsigned short*)(ws);             // 512KB bf16 [256,1024]
  unsigned short* xtb = (unsigned short*)(ws + 524288);    // 1MB bf16 [256,2048]
  unsigned short* xcb = (unsigned short*)(ws + 1572864);   // 1MB bf16 [256,2048]
  unsigned short* yb  = (unsigned short*)(ws + 2621440);   // 512KB bf16 [256,1024]
  float* xt  = (float*)(ws + 3145728);                     // 2MB [256,2048]
  float* sr  = (float*)(ws + 5242880);                     // 1MB silu(r_t)
  float* qb  = (float*)(ws + 6291456);                     // 1MB
  float* kb  = (float*)(ws + 7340032);                     // 1MB (pre-scaled)
  float* vb  = (float*)(ws + 8388608);                     // 1MB
  float* ob  = (float*)(ws + 9437184);                     // 1MB sigmoid(o)
  float* skb = (float*)(ws + 10485760);                    // 1MB
  float* itb = (float*)(ws + 11534336);                    // 8KB [256,8]
  float* ftb = (float*)(ws + 11542528);                    // 8KB [256,8]
  // bf16 weights (28.06 MB)
  unsigned short* wb = (unsigned short*)(ws + 11550720);
  unsigned short* wupl_b = wb;                  // 2M elems
  unsigned short* wupr_b = wupl_b + 2097152;    // 1M
  unsigned short* wdown_b= wupr_b + 1048576;    // 1M
  unsigned short* wskip_b= wdown_b + 1048576;   // 2M
  unsigned short* wq_b   = wskip_b + 2097152;   // 2M
  unsigned short* wk_b   = wq_b + 2097152;      // 2M
  unsigned short* wv_b   = wk_b + 2097152;      // 2M
  unsigned short* wo_b   = wv_b + 2097152;      // 2M
  unsigned short* wi_b   = wo_b + 2097152;      // 16K
  unsigned short* wf_b   = wi_b + 16384;        // 16K

  PrepSegs pp = {};
  pp.nseg = 10;
  pp.src[0] = W_upl;  pp.dst[0] = wupl_b;  pp.blk0[0] = 0;     // 2M -> 256 blocks
  pp.src[1] = W_upr;  pp.dst[1] = wupr_b;  pp.blk0[1] = 256;   // 1M -> 128
  pp.src[2] = W_down; pp.dst[2] = wdown_b; pp.blk0[2] = 384;   // 1M -> 128
  pp.src[3] = W_skip; pp.dst[3] = wskip_b; pp.blk0[3] = 512;   // 2M -> 256
  pp.src[4] = W_q;    pp.dst[4] = wq_b;    pp.blk0[4] = 768;
  pp.src[5] = W_k;    pp.dst[5] = wk_b;    pp.blk0[5] = 1024;
  pp.src[6] = W_v;    pp.dst[6] = wv_b;    pp.blk0[6] = 1280;
  pp.src[7] = W_o;    pp.dst[7] = wo_b;    pp.blk0[7] = 1536;
  pp.src[8] = W_i;    pp.dst[8] = wi_b;    pp.blk0[8] = 1792;  // 16K -> 2
  pp.src[9] = W_f;    pp.dst[9] = wf_b;    pp.blk0[9] = 1794;  // 16K -> 2
  prep_kernel<<<1796, 256, 0, stream>>>(pp);

  ln_kernel<<<256, 256, 0, stream>>>(seq, ln_g, ln_b, xnb);

  GemmSegs g1 = {};
  g1.nseg = 2; g1.K = 1024;
  g1.A[0] = xnb; g1.W[0] = wupl_b; g1.bias[0] = b_upl; g1.out[0] = xt;
  g1.N[0] = 2048; g1.tile0[0] = 0;  g1.act[0] = 0; g1.scale[0] = 1.f;
  g1.A[1] = xnb; g1.W[1] = wupr_b; g1.bias[1] = b_upr; g1.out[1] = sr;
  g1.N[1] = 1024; g1.tile0[1] = 32; g1.act[1] = 1; g1.scale[1] = 1.f;  // silu(r_t)
  gemm_multi<<<48 * 4, 256, 0, stream>>>(g1);

  conv_kernel<<<256, 256, 0, stream>>>(xt, conv_w, conv_b, xcb, xtb);

  GemmSegs g2 = {};
  g2.nseg = 7; g2.K = 2048;
  g2.A[0] = xcb; g2.W[0] = wq_b;    g2.bias[0] = b_q;    g2.out[0] = qb;
  g2.N[0] = 1024; g2.tile0[0] = 0;  g2.act[0] = 0; g2.scale[0] = 1.f;
  g2.A[1] = xcb; g2.W[1] = wk_b;    g2.bias[1] = b_k;    g2.out[1] = kb;
  g2.N[1] = 1024; g2.tile0[1] = 16; g2.act[1] = 0; g2.scale[1] = 0.088388347648318447f; // 1/sqrt(128)
  g2.A[2] = xtb; g2.W[2] = wv_b;    g2.bias[2] = b_v;    g2.out[2] = vb;
  g2.N[2] = 1024; g2.tile0[2] = 32; g2.act[2] = 0; g2.scale[2] = 1.f;
  g2.A[3] = xtb; g2.W[3] = wo_b;    g2.bias[3] = b_o;    g2.out[3] = ob;
  g2.N[3] = 1024; g2.tile0[3] = 48; g2.act[3] = 2; g2.scale[3] = 1.f;  // sigmoid
  g2.A[4] = xcb; g2.W[4] = wskip_b; g2.bias[4] = nullptr; g2.out[4] = skb;
  g2.N[4] = 1024; g2.tile0[4] = 64; g2.act[4] = 0; g2.scale[4] = 1.f;
  g2.A[5] = xcb; g2.W[5] = wi_b;    g2.bias[5] = b_i;    g2.out[5] = itb;
  g2.N[5] = 8;    g2.tile0[5] = 80; g2.act[5] = 0; g2.scale[5] = 1.f;
  g2.A[6] = xcb; g2.W[6] = wf_b;    g2.bias[6] = b_f;    g2.out[6] = ftb;
  g2.N[6] = 8;    g2.tile0[6] = 81; g2.act[6] = 0; g2.scale[6] = 1.f;
  gemm_multi<<<82 * 4, 256, 0, stream>>>(g2);

  cell_kernel<<<2048, 256, 0, stream>>>(c0, n0, m0, qb, kb, vb, ob, skb, sr,
                                        itb, ftb, gn_g, gn_b, ct, nt, mt, yb);

  GemmSegs g3 = {};
  g3.nseg = 1; g3.K = 1024;
  g3.A[0] = yb; g3.W[0] = wdown_b; g3.bias[0] = b_down; g3.add[0] = seq; g3.out[0] = out;
  g3.N[0] = 1024; g3.tile0[0] = 0; g3.act[0] = 3; g3.scale[0] = 1.f;   // + b_down + seq
  gemm_multi<<<16 * 4, 256, 0, stream>>>(g3);
}